// Round 8
// baseline (275.575 us; speedup 1.0000x reference)
//
#include <hip/hip_runtime.h>
#include <hip/hip_fp16.h>

#define D 128          // feature dim (D_IN == D_H)
#define BSHIFT 9       // bin bucket = dst >> 9 (512 nodes per bucket)
#define MAXB 512       // max bin buckets (N up to 262144)
#define CHUNK 8192     // edges per bin_k block (16 per thread, 512 threads)
#define CAP 12288      // slots per bin bucket (mean 8163, sigma ~90)
#define CAPQ 2560      // LDS elist slots per 128-node quarter (mean 2041, +11 sigma)
#define SMASK 0x7FFFFFu
#define GP 8           // LDS pad (halves) -> row stride 272 B, 2-way-conflict-free

typedef _Float16 f16x8 __attribute__((ext_vector_type(8)));
typedef float f32x4 __attribute__((ext_vector_type(4)));

// ---------------- setup: W1 transpose to fp16 + zero bucket cursors ----------------
__global__ void setup_k(const float* __restrict__ W1, _Float16* __restrict__ w1t,
                        int* __restrict__ bcur) {
    int idx = blockIdx.x * 256 + threadIdx.x;   // 16384 total
    int k = idx >> 7, n = idx & 127;
    w1t[n * 128 + k] = (_Float16)W1[idx];
    if (idx < MAXB) bcur[idx] = 0;
}

// ---------------- pass 1: bin edges into per-bucket regions ----------------
// pairs[slot] = (dstLocal << 23) | src ; bcur[b] = fill count.
__global__ __launch_bounds__(512) void bin_k(const int* __restrict__ src,
                                             const int* __restrict__ dst,
                                             int* __restrict__ bcur,
                                             unsigned int* __restrict__ pairs, int E) {
    __shared__ int h[MAXB];
    __shared__ int cur[MAXB];
    if (threadIdx.x < MAXB) h[threadIdx.x] = 0;
    __syncthreads();
    const int base = blockIdx.x * CHUNK;
    int s_[16], d_[16];
    int n = 0;
#pragma unroll
    for (int u = 0; u < 16; ++u) {
        int e = base + u * 512 + threadIdx.x;
        if (e < E) {
            s_[u] = src[e];
            d_[u] = dst[e];
            atomicAdd(&h[d_[u] >> BSHIFT], 1);
            n = u + 1;                      // validity is monotone in u for fixed tid
        }
    }
    __syncthreads();
    if (threadIdx.x < MAXB) {
        int i = threadIdx.x;
        cur[i] = h[i] ? (i * CAP + atomicAdd(&bcur[i], h[i])) : 0;
    }
    __syncthreads();
#pragma unroll
    for (int u = 0; u < 16; ++u) {
        if (u < n) {
            int b = d_[u] >> BSHIFT;
            int pos = atomicAdd(&cur[b], 1);
            if (pos - b * CAP < CAP)        // overflow guard (never taken for this dist)
                pairs[pos] = ((unsigned int)(d_[u] & ((1 << BSHIFT) - 1)) << 23) |
                             (unsigned int)s_[u];
        }
    }
}

// ---------------- MFMA GEMM + fused deg/dis ----------------
// Block b = rows [b*128, b*128+128) = quarter q=b&3 of bin bucket b>>2.
// Streams parent bucket's pairs, filters, hists 128 -> dis; then
// h1s[r][c] = fp16( dis[r] * sum_k x[r][k] * W1[k][c] ).
__global__ __launch_bounds__(256) void gemm_k(const float* __restrict__ x,
                                              const _Float16* __restrict__ w1t,
                                              const unsigned int* __restrict__ pairs,
                                              const int* __restrict__ bcur,
                                              float* __restrict__ dis,
                                              __half2* __restrict__ h1s2, int N) {
    __shared__ _Float16 xs[128][128 + GP];
    __shared__ _Float16 ws[128][128 + GP];   // ws[n][k]
    __shared__ int hist[128];
    __shared__ float disl[128];

    const int tid = threadIdx.x;
    const int row0 = blockIdx.x * 128;
    const int parent = blockIdx.x >> 2;
    const unsigned int q = blockIdx.x & 3;

    if (tid < 128) hist[tid] = 0;
    __syncthreads();
    {
        int cnt = bcur[parent]; cnt = cnt < CAP ? cnt : CAP;
        const unsigned int* bp = pairs + parent * CAP;
        for (int e = tid; e < cnt; e += 256) {
            unsigned int p = bp[e];
            unsigned int dq = p >> 23;
            if ((dq >> 7) == q) atomicAdd(&hist[dq & 127], 1);
        }
    }

    // stage x (fp32 -> fp16): 128 rows x 32 float4, 16 per thread
#pragma unroll
    for (int u = 0; u < 16; ++u) {
        int f = u * 256 + tid;
        int r = f >> 5, c4 = f & 31;
        int rg = row0 + r; rg = rg < N ? rg : N - 1;
        float4 v = ((const float4*)(x + (size_t)rg * D))[c4];
        union { _Float16 h[4]; uint2 u2; } tmp;
        tmp.h[0] = (_Float16)v.x; tmp.h[1] = (_Float16)v.y;
        tmp.h[2] = (_Float16)v.z; tmp.h[3] = (_Float16)v.w;
        *(uint2*)&xs[r][c4 * 4] = tmp.u2;
    }
    // stage w1t (already fp16, row-major [n][k]): 128 rows x 16 int4, 8 per thread
#pragma unroll
    for (int u = 0; u < 8; ++u) {
        int f = u * 256 + tid;
        int r = f >> 4, c8 = f & 15;
        int4 v = ((const int4*)(w1t + r * 128))[c8];
        *(int4*)&ws[r][c8 * 8] = v;
    }
    __syncthreads();

    if (tid < 128) {
        float dv = rsqrtf((float)(hist[tid] + 1));   // +1 self-loop
        disl[tid] = dv;
        if (row0 + tid < N) dis[row0 + tid] = dv;
    }

    const int wave = tid >> 6, lane = tid & 63;
    const int qr = lane & 15;       // A-row / B-col / D-col index
    const int quad = lane >> 4;     // k-subgroup, D-row group
    const int m0 = wave * 32;       // 32 rows per wave (2 M-tiles)

    f32x4 acc[2][8] = {};
#pragma unroll
    for (int kt = 0; kt < 4; ++kt) {
        const int kk = kt * 32 + quad * 8;
        f16x8 a0 = *(const f16x8*)&xs[m0 + qr][kk];
        f16x8 a1 = *(const f16x8*)&xs[m0 + 16 + qr][kk];
#pragma unroll
        for (int n = 0; n < 8; ++n) {
            f16x8 b = *(const f16x8*)&ws[n * 16 + qr][kk];
            acc[0][n] = __builtin_amdgcn_mfma_f32_16x16x32_f16(a0, b, acc[0][n], 0, 0, 0);
            acc[1][n] = __builtin_amdgcn_mfma_f32_16x16x32_f16(a1, b, acc[1][n], 0, 0, 0);
        }
    }

    __syncthreads();   // xs reads done; also orders disl writes -> reads below
#pragma unroll
    for (int mt = 0; mt < 2; ++mt)
#pragma unroll
        for (int r = 0; r < 4; ++r) {
            int row = m0 + mt * 16 + quad * 4 + r;
            float dv = disl[row];
#pragma unroll
            for (int n = 0; n < 8; ++n)
                xs[row][n * 16 + qr] = (_Float16)(acc[mt][n][r] * dv);
        }
    __syncthreads();

    // coalesced copy out: 128 rows x 16 int4, 8 per thread
#pragma unroll
    for (int u = 0; u < 8; ++u) {
        int f = u * 256 + tid;
        int r = f >> 4, c8 = f & 15;
        int rg = row0 + r;
        if (rg < N)
            *(int4*)((_Float16*)h1s2 + (size_t)rg * D + c8 * 8) = *(int4*)&xs[r][c8 * 8];
    }
}

// ---------------- agg1: LDS-sorted quarter bucket + wave-per-node gather ----------
// Block = 128 nodes. Phases: stream+filter+hist -> scan -> scatter srcs to LDS
// elist -> R7-proven register-accumulating gather + b1/relu/W2 epilogue.
__global__ __launch_bounds__(256) void agg1_k(const __half2* __restrict__ h1s2,
                                              const unsigned int* __restrict__ pairs,
                                              const int* __restrict__ bcur,
                                              const float* __restrict__ b1,
                                              const float* __restrict__ W2,
                                              float* __restrict__ g, int N) {
    __shared__ int hist[128];
    __shared__ int scan[128];
    __shared__ int offsE[128];
    __shared__ int cur[128];
    __shared__ int elist[CAPQ];

    const int tid = threadIdx.x;
    const int lane = tid & 63;
    const int vb = blockIdx.x * 128;
    const int parent = blockIdx.x >> 2;
    const unsigned int q = blockIdx.x & 3;

    int cnt = bcur[parent]; cnt = cnt < CAP ? cnt : CAP;
    const unsigned int* bp = pairs + parent * CAP;

    if (tid < 128) hist[tid] = 0;
    __syncthreads();
    // phase A: filter + histogram
    for (int e = tid; e < cnt; e += 256) {
        unsigned int p = bp[e];
        unsigned int dq = p >> 23;
        if ((dq >> 7) == q) atomicAdd(&hist[dq & 127], 1);
    }
    __syncthreads();
    // phase B: inclusive scan of 128 (Hillis-Steele, 128 active)
    if (tid < 128) scan[tid] = hist[tid];
    __syncthreads();
    for (int o = 1; o < 128; o <<= 1) {
        int a = 0;
        if (tid < 128 && tid >= o) a = scan[tid - o];
        __syncthreads();
        if (tid < 128) scan[tid] += a;
        __syncthreads();
    }
    if (tid < 128) {
        int b = scan[tid] - hist[tid];       // exclusive
        offsE[tid] = b;
        cur[tid] = b;
    }
    __syncthreads();
    // phase C: scatter srcs into per-node-contiguous LDS elist
    for (int e = tid; e < cnt; e += 256) {
        unsigned int p = bp[e];
        unsigned int dq = p >> 23;
        if ((dq >> 7) == q) {
            int pos = atomicAdd(&cur[dq & 127], 1);
            if (pos < CAPQ) elist[pos] = (int)(p & SMASK);
        }
    }
    __syncthreads();

    // phase D: wave-per-node gather (identical structure to R7's proven loop)
    const int wave = tid >> 6;
    const float2 bb = ((const float2*)b1)[lane];
    const float2 w2 = ((const float2*)W2)[lane];
    for (int i = wave; i < 128; i += 4) {
        int v = vb + i;
        if (v >= N) continue;
        int beg = __builtin_amdgcn_readfirstlane(offsE[i]);
        int dg  = __builtin_amdgcn_readfirstlane(hist[i]);
        int end = beg + dg;
        end = end < CAPQ ? end : CAPQ;
        beg = beg < CAPQ ? beg : CAPQ;
        float dv = rsqrtf((float)(dg + 1));  // same formula as gemm_k -> consistent

        __half2 hs = h1s2[(size_t)v * 64 + lane];   // self (h1s carries dis[src])
        float ax = __low2float(hs), ay = __high2float(hs);

        int j = beg;
        for (; j + 8 <= end; j += 8) {               // 8 gathers in flight
            int4 sa = *(const int4*)&elist[j];
            int4 sb = *(const int4*)&elist[j + 4];
            __half2 h0 = h1s2[(size_t)sa.x * 64 + lane];
            __half2 h1 = h1s2[(size_t)sa.y * 64 + lane];
            __half2 h2 = h1s2[(size_t)sa.z * 64 + lane];
            __half2 h3 = h1s2[(size_t)sa.w * 64 + lane];
            __half2 h4 = h1s2[(size_t)sb.x * 64 + lane];
            __half2 h5 = h1s2[(size_t)sb.y * 64 + lane];
            __half2 h6 = h1s2[(size_t)sb.z * 64 + lane];
            __half2 h7 = h1s2[(size_t)sb.w * 64 + lane];
            ax += __low2float(h0) + __low2float(h1) + __low2float(h2) + __low2float(h3)
                + __low2float(h4) + __low2float(h5) + __low2float(h6) + __low2float(h7);
            ay += __high2float(h0) + __high2float(h1) + __high2float(h2) + __high2float(h3)
                + __high2float(h4) + __high2float(h5) + __high2float(h6) + __high2float(h7);
        }
        for (; j < end; ++j) {
            __half2 h0 = h1s2[(size_t)elist[j] * 64 + lane];
            ax += __low2float(h0);
            ay += __high2float(h0);
        }

        float vx = fmaxf(fmaf(dv, ax, bb.x), 0.f);
        float vy = fmaxf(fmaf(dv, ay, bb.y), 0.f);
        float p = vx * w2.x + vy * w2.y;
#pragma unroll
        for (int o = 32; o >= 1; o >>= 1) p += __shfl_xor(p, o, 64);
        if (lane == 0) g[v] = dv * p;
    }
}

// ---------------- agg2: bucket-resident scalar accumulate ----------------
__global__ __launch_bounds__(256) void agg2_k(const float* __restrict__ g,
                                              const unsigned int* __restrict__ pairs,
                                              const int* __restrict__ bcur,
                                              const float* __restrict__ dis,
                                              const float* __restrict__ b2,
                                              float* __restrict__ out, int N) {
    __shared__ float acc[128];
    const int t = threadIdx.x;
    const int vb = blockIdx.x * 128;
    const int parent = blockIdx.x >> 2;
    const unsigned int q = blockIdx.x & 3;
    if (t < 128) acc[t] = 0.f;
    __syncthreads();
    int cnt = bcur[parent]; cnt = cnt < CAP ? cnt : CAP;
    const unsigned int* bp = pairs + parent * CAP;
    for (int e = t; e < cnt; e += 256) {
        unsigned int p = bp[e];
        unsigned int dq = p >> 23;
        if ((dq >> 7) == q) atomicAdd(&acc[dq & 127], g[p & SMASK]);
    }
    __syncthreads();
    if (t < 128) {
        int v = vb + t;
        if (v < N) out[v] = fmaf(dis[v], acc[t] + g[v], b2[0]);
    }
}

// ---------------- launch ----------------

extern "C" void kernel_launch(void* const* d_in, const int* in_sizes, int n_in,
                              void* d_out, int out_size, void* d_ws, size_t ws_size,
                              hipStream_t stream) {
    const float* x  = (const float*)d_in[0];
    const int*   ei = (const int*)d_in[1];
    const float* W1 = (const float*)d_in[2];
    const float* b1 = (const float*)d_in[3];
    const float* W2 = (const float*)d_in[4];
    const float* b2 = (const float*)d_in[5];
    float* out = (float*)d_out;

    const int N = in_sizes[0] / D;
    const int E = in_sizes[1] / 2;
    const int* srcp = ei;
    const int* dstp = ei + E;
    const int nbuck = (N + (1 << BSHIFT) - 1) >> BSHIFT;   // 196 bin buckets
    const int ngrp = (N + 127) / 128;                      // 782 quarter blocks

    char* p = (char*)d_ws;
    auto alloc = [&](size_t bytes) {
        void* q = (void*)p;
        p += (bytes + 255) & ~(size_t)255;
        return q;
    };
    __half2*      h1s2  = (__half2*)alloc((size_t)N * D * sizeof(__half));
    float*        g     = (float*)alloc((size_t)N * sizeof(float));
    float*        dis   = (float*)alloc((size_t)N * sizeof(float));
    unsigned int* pairs = (unsigned int*)alloc((size_t)nbuck * CAP * sizeof(unsigned int));
    _Float16*     w1t   = (_Float16*)alloc((size_t)D * D * sizeof(_Float16));
    int*          bcur  = (int*)alloc(MAXB * sizeof(int));

    setup_k<<<(D * D) / 256, 256, 0, stream>>>(W1, w1t, bcur);
    bin_k<<<(E + CHUNK - 1) / CHUNK, 512, 0, stream>>>(srcp, dstp, bcur, pairs, E);
    gemm_k<<<ngrp, 256, 0, stream>>>(x, w1t, pairs, bcur, dis, h1s2, N);
    agg1_k<<<ngrp, 256, 0, stream>>>(h1s2, pairs, bcur, b1, W2, g, N);
    agg2_k<<<ngrp, 256, 0, stream>>>(g, pairs, bcur, dis, b2, out, N);
}

// Round 9
// 236.430 us; speedup vs baseline: 1.1656x; 1.1656x over previous
//
#include <hip/hip_runtime.h>
#include <hip/hip_fp16.h>

#define D 128          // feature dim (D_IN == D_H)
#define BSHIFT 9       // bin bucket = dst >> 9 (512 nodes per bucket)
#define MAXB 512       // max bin buckets (N up to 262144)
#define CHUNK 8192     // edges per bin_k block (16 per thread, 512 threads)
#define CAP 12288      // slots per bin bucket (mean 8163, sigma ~90 -> +45 sigma)
#define CAPQ 2560      // global edge_src slots per 128-node quarter (mean 2041, +11 sigma)
#define SMASK 0x7FFFFFu
#define GP 8           // LDS pad (halves) -> row stride 272 B, 2-way-conflict-free

typedef _Float16 f16x8 __attribute__((ext_vector_type(8)));
typedef float f32x4 __attribute__((ext_vector_type(4)));

// ---------------- setup: W1 transpose to fp16 + zero bucket cursors ----------------
__global__ void setup_k(const float* __restrict__ W1, _Float16* __restrict__ w1t,
                        int* __restrict__ bcur) {
    int idx = blockIdx.x * 256 + threadIdx.x;   // 16384 total
    int k = idx >> 7, n = idx & 127;
    w1t[n * 128 + k] = (_Float16)W1[idx];
    if (idx < MAXB) bcur[idx] = 0;
}

// ---------------- pass 1: bin edges into per-bucket regions ----------------
// pairs[slot] = (dstLocal << 23) | src ; bcur[b] = fill count.
__global__ __launch_bounds__(512) void bin_k(const int* __restrict__ src,
                                             const int* __restrict__ dst,
                                             int* __restrict__ bcur,
                                             unsigned int* __restrict__ pairs, int E) {
    __shared__ int h[MAXB];
    __shared__ int cur[MAXB];
    if (threadIdx.x < MAXB) h[threadIdx.x] = 0;
    __syncthreads();
    const int base = blockIdx.x * CHUNK;
    int s_[16], d_[16];
    int n = 0;
#pragma unroll
    for (int u = 0; u < 16; ++u) {
        int e = base + u * 512 + threadIdx.x;
        if (e < E) {
            s_[u] = src[e];
            d_[u] = dst[e];
            atomicAdd(&h[d_[u] >> BSHIFT], 1);
            n = u + 1;                      // validity is monotone in u for fixed tid
        }
    }
    __syncthreads();
    if (threadIdx.x < MAXB) {
        int i = threadIdx.x;
        cur[i] = h[i] ? (i * CAP + atomicAdd(&bcur[i], h[i])) : 0;
    }
    __syncthreads();
#pragma unroll
    for (int u = 0; u < 16; ++u) {
        if (u < n) {
            int b = d_[u] >> BSHIFT;
            int pos = atomicAdd(&cur[b], 1);
            if (pos - b * CAP < CAP)        // overflow guard (never taken for this dist)
                pairs[pos] = ((unsigned int)(d_[u] & ((1 << BSHIFT) - 1)) << 23) |
                             (unsigned int)s_[u];
        }
    }
}

// ---------------- prep: per-quarter CSR build + MFMA GEMM (fused) ----------------
// Block = quarter q=b&3 of bin bucket b>>2 = rows [b*128, b*128+128).
// Phase 1: stream parent pairs, filter quarter, hist 128 -> deg/dis/offs;
//          scan; scatter edge_src into private global region blockIdx*CAPQ.
// Phase 2: h1s[r][c] = fp16( dis[r] * sum_k x[r][k] * W1[k][c] )  (MFMA).
__global__ __launch_bounds__(256) void prep_k(const float* __restrict__ x,
                                              const _Float16* __restrict__ w1t,
                                              const unsigned int* __restrict__ pairs,
                                              const int* __restrict__ bcur,
                                              int* __restrict__ offs,
                                              int* __restrict__ deg,
                                              float* __restrict__ dis,
                                              int* __restrict__ edge_src,
                                              __half2* __restrict__ h1s2, int N) {
    __shared__ _Float16 xs[128][128 + GP];
    __shared__ _Float16 ws[128][128 + GP];   // ws[n][k]
    __shared__ int hist[128];
    __shared__ int scan[128];
    __shared__ int cur[128];
    __shared__ float disl[128];

    const int tid = threadIdx.x;
    const int row0 = blockIdx.x * 128;
    const int parent = blockIdx.x >> 2;
    const unsigned int q = blockIdx.x & 3;
    const int qbase = blockIdx.x * CAPQ;

    int cnt = bcur[parent]; cnt = cnt < CAP ? cnt : CAP;
    const unsigned int* bp = pairs + parent * CAP;

    if (tid < 128) hist[tid] = 0;
    __syncthreads();
    // phase 1a: filter + histogram
    for (int e = tid; e < cnt; e += 256) {
        unsigned int p = bp[e];
        unsigned int dq = p >> 23;
        if ((dq >> 7) == q) atomicAdd(&hist[dq & 127], 1);
    }
    __syncthreads();
    // phase 1b: inclusive scan of 128
    if (tid < 128) scan[tid] = hist[tid];
    __syncthreads();
    for (int o = 1; o < 128; o <<= 1) {
        int a = 0;
        if (tid < 128 && tid >= o) a = scan[tid - o];
        __syncthreads();
        if (tid < 128) scan[tid] += a;
        __syncthreads();
    }
    if (tid < 128) {
        int c = hist[tid];
        int b = scan[tid] - c;               // exclusive
        cur[tid] = b;
        float dv = rsqrtf((float)(c + 1));   // +1 self-loop
        disl[tid] = dv;
        int v = row0 + tid;
        if (v < N) {
            offs[v] = qbase + b;
            deg[v] = c;
            dis[v] = dv;
        }
    }
    __syncthreads();
    // phase 1c: scatter srcs into private global region (coalesced-ish, 10 KB)
    for (int e = tid; e < cnt; e += 256) {
        unsigned int p = bp[e];
        unsigned int dq = p >> 23;
        if ((dq >> 7) == q) {
            int pos = atomicAdd(&cur[dq & 127], 1);
            if (pos < CAPQ) edge_src[qbase + pos] = (int)(p & SMASK);
        }
    }

    // phase 2: GEMM. stage x (fp32 -> fp16): 128 rows x 32 float4, 16 per thread
#pragma unroll
    for (int u = 0; u < 16; ++u) {
        int f = u * 256 + tid;
        int r = f >> 5, c4 = f & 31;
        int rg = row0 + r; rg = rg < N ? rg : N - 1;
        float4 v = ((const float4*)(x + (size_t)rg * D))[c4];
        union { _Float16 h[4]; uint2 u2; } tmp;
        tmp.h[0] = (_Float16)v.x; tmp.h[1] = (_Float16)v.y;
        tmp.h[2] = (_Float16)v.z; tmp.h[3] = (_Float16)v.w;
        *(uint2*)&xs[r][c4 * 4] = tmp.u2;
    }
    // stage w1t (already fp16, row-major [n][k]): 128 rows x 16 int4, 8 per thread
#pragma unroll
    for (int u = 0; u < 8; ++u) {
        int f = u * 256 + tid;
        int r = f >> 4, c8 = f & 15;
        int4 v = ((const int4*)(w1t + r * 128))[c8];
        *(int4*)&ws[r][c8 * 8] = v;
    }
    __syncthreads();

    const int wave = tid >> 6, lane = tid & 63;
    const int qr = lane & 15;       // A-row / B-col / D-col index
    const int quad = lane >> 4;     // k-subgroup, D-row group
    const int m0 = wave * 32;       // 32 rows per wave (2 M-tiles)

    f32x4 acc[2][8] = {};
#pragma unroll
    for (int kt = 0; kt < 4; ++kt) {
        const int kk = kt * 32 + quad * 8;
        f16x8 a0 = *(const f16x8*)&xs[m0 + qr][kk];
        f16x8 a1 = *(const f16x8*)&xs[m0 + 16 + qr][kk];
#pragma unroll
        for (int n = 0; n < 8; ++n) {
            f16x8 b = *(const f16x8*)&ws[n * 16 + qr][kk];
            acc[0][n] = __builtin_amdgcn_mfma_f32_16x16x32_f16(a0, b, acc[0][n], 0, 0, 0);
            acc[1][n] = __builtin_amdgcn_mfma_f32_16x16x32_f16(a1, b, acc[1][n], 0, 0, 0);
        }
    }

    __syncthreads();   // all waves done reading xs before reuse
#pragma unroll
    for (int mt = 0; mt < 2; ++mt)
#pragma unroll
        for (int r = 0; r < 4; ++r) {
            int row = m0 + mt * 16 + quad * 4 + r;
            float dv = disl[row];
#pragma unroll
            for (int n = 0; n < 8; ++n)
                xs[row][n * 16 + qr] = (_Float16)(acc[mt][n][r] * dv);
        }
    __syncthreads();

    // coalesced copy out: 128 rows x 16 int4, 8 per thread
#pragma unroll
    for (int u = 0; u < 8; ++u) {
        int f = u * 256 + tid;
        int r = f >> 4, c8 = f & 15;
        int rg = row0 + r;
        if (rg < N)
            *(int4*)((_Float16*)h1s2 + (size_t)rg * D + c8 * 8) = *(int4*)&xs[r][c8 * 8];
    }
}

// ---------------- fused: aggregate layer1 + b1 + relu + W2 matvec ----------------
// one WAVE per node (4 nodes / 256-block); lane l holds features 2l, 2l+1 (half2).
// (R7-proven: 62 µs, fabric-bound)

__global__ __launch_bounds__(256) void agg1_k(const __half2* __restrict__ h1s2,
                                              const int* __restrict__ edge_src,
                                              const int* __restrict__ offs,
                                              const int* __restrict__ deg,
                                              const float* __restrict__ dis,
                                              const float* __restrict__ b1,
                                              const float* __restrict__ W2,
                                              float* __restrict__ g, int N) {
    const int lane = threadIdx.x & 63;
    int v = blockIdx.x * 4 + (threadIdx.x >> 6);
    if (v >= N) return;
    v = __builtin_amdgcn_readfirstlane(v);           // force SGPR: scalar loads below

    __half2 hs = h1s2[v * 64 + lane];                // self-loop (h1s carries dis[src])
    float ax = __low2float(hs), ay = __high2float(hs);

    int beg = __builtin_amdgcn_readfirstlane(offs[v]);
    int end = beg + __builtin_amdgcn_readfirstlane(deg[v]);

    int i = beg;
    for (; i + 8 <= end; i += 8) {                   // 8 gathers in flight
        __half2 h0 = h1s2[edge_src[i + 0] * 64 + lane];
        __half2 h1 = h1s2[edge_src[i + 1] * 64 + lane];
        __half2 h2 = h1s2[edge_src[i + 2] * 64 + lane];
        __half2 h3 = h1s2[edge_src[i + 3] * 64 + lane];
        __half2 h4 = h1s2[edge_src[i + 4] * 64 + lane];
        __half2 h5 = h1s2[edge_src[i + 5] * 64 + lane];
        __half2 h6 = h1s2[edge_src[i + 6] * 64 + lane];
        __half2 h7 = h1s2[edge_src[i + 7] * 64 + lane];
        ax += __low2float(h0) + __low2float(h1) + __low2float(h2) + __low2float(h3)
            + __low2float(h4) + __low2float(h5) + __low2float(h6) + __low2float(h7);
        ay += __high2float(h0) + __high2float(h1) + __high2float(h2) + __high2float(h3)
            + __high2float(h4) + __high2float(h5) + __high2float(h6) + __high2float(h7);
    }
    for (; i < end; ++i) {
        __half2 h0 = h1s2[edge_src[i] * 64 + lane];
        ax += __low2float(h0);
        ay += __high2float(h0);
    }

    const float dv = dis[v];
    const float2 bb = ((const float2*)b1)[lane];
    const float2 w2 = ((const float2*)W2)[lane];
    float vx = fmaxf(fmaf(dv, ax, bb.x), 0.f);
    float vy = fmaxf(fmaf(dv, ay, bb.y), 0.f);
    float p = vx * w2.x + vy * w2.y;
#pragma unroll
    for (int o = 32; o >= 1; o >>= 1) p += __shfl_xor(p, o, 64);
    if (lane == 0) g[v] = dv * p;
}

// ---------------- layer-2 scalar aggregation ----------------

__global__ void agg2_k(const float* __restrict__ g, const int* __restrict__ edge_src,
                       const int* __restrict__ offs, const int* __restrict__ deg,
                       const float* __restrict__ dis, const float* __restrict__ b2,
                       float* __restrict__ out, int N) {
    int v = blockIdx.x * 256 + threadIdx.x;
    if (v >= N) return;
    float acc = g[v];                      // self-loop (g already has dis[src])
    const int beg = offs[v];
    const int end = beg + deg[v];
    for (int i = beg; i < end; ++i) acc += g[edge_src[i]];
    out[v] = fmaf(dis[v], acc, b2[0]);
}

// ---------------- launch ----------------

extern "C" void kernel_launch(void* const* d_in, const int* in_sizes, int n_in,
                              void* d_out, int out_size, void* d_ws, size_t ws_size,
                              hipStream_t stream) {
    const float* x  = (const float*)d_in[0];
    const int*   ei = (const int*)d_in[1];
    const float* W1 = (const float*)d_in[2];
    const float* b1 = (const float*)d_in[3];
    const float* W2 = (const float*)d_in[4];
    const float* b2 = (const float*)d_in[5];
    float* out = (float*)d_out;

    const int N = in_sizes[0] / D;
    const int E = in_sizes[1] / 2;
    const int* srcp = ei;
    const int* dstp = ei + E;
    const int nbuck = (N + (1 << BSHIFT) - 1) >> BSHIFT;   // 196 bin buckets
    const int ngrp = (N + 127) / 128;                      // 782 quarter blocks

    char* p = (char*)d_ws;
    auto alloc = [&](size_t bytes) {
        void* q = (void*)p;
        p += (bytes + 255) & ~(size_t)255;
        return q;
    };
    __half2*      h1s2     = (__half2*)alloc((size_t)N * D * sizeof(__half));
    float*        g        = (float*)alloc((size_t)N * sizeof(float));
    float*        dis      = (float*)alloc((size_t)N * sizeof(float));
    int*          offs     = (int*)alloc((size_t)N * sizeof(int));
    int*          deg      = (int*)alloc((size_t)N * sizeof(int));
    int*          edge_src = (int*)alloc((size_t)ngrp * CAPQ * sizeof(int));
    unsigned int* pairs    = (unsigned int*)alloc((size_t)nbuck * CAP * sizeof(unsigned int));
    _Float16*     w1t      = (_Float16*)alloc((size_t)D * D * sizeof(_Float16));
    int*          bcur     = (int*)alloc(MAXB * sizeof(int));

    const int nb = (N + 255) / 256;

    setup_k<<<(D * D) / 256, 256, 0, stream>>>(W1, w1t, bcur);
    bin_k<<<(E + CHUNK - 1) / CHUNK, 512, 0, stream>>>(srcp, dstp, bcur, pairs, E);
    prep_k<<<ngrp, 256, 0, stream>>>(x, w1t, pairs, bcur, offs, deg, dis,
                                     edge_src, h1s2, N);
    agg1_k<<<(N + 3) / 4, 256, 0, stream>>>(h1s2, edge_src, offs, deg, dis, b1, W2, g, N);
    agg2_k<<<nb, 256, 0, stream>>>(g, edge_src, offs, deg, dis, b2, out, N);
}

// Round 10
// 227.037 us; speedup vs baseline: 1.2138x; 1.0414x over previous
//
#include <hip/hip_runtime.h>
#include <hip/hip_fp16.h>

#define D 128          // feature dim (D_IN == D_H)
#define BSHIFT 9       // bucket = dst >> 9 (512 nodes per bucket)
#define MAXB 512       // max buckets supported (N up to 262144)
#define CHUNK 8192     // edges per bin_k block (16 per thread, 512 threads)
#define CAP 12288      // fixed slots per bucket (mean 8163, sigma ~90 -> 45 sigma slack)
#define GP 8           // LDS pad (halves) -> row stride 272 B, 2-way-conflict-free

typedef _Float16 f16x8 __attribute__((ext_vector_type(8)));
typedef float f32x4 __attribute__((ext_vector_type(4)));

// ---------------- setup: W1 transpose to fp16 + zero bucket cursors ----------------
__global__ void setup_k(const float* __restrict__ W1, _Float16* __restrict__ w1t,
                        int* __restrict__ bcur) {
    int idx = blockIdx.x * 256 + threadIdx.x;   // 16384 total
    int k = idx >> 7, n = idx & 127;
    w1t[n * 128 + k] = (_Float16)W1[idx];
    if (idx < MAXB) bcur[idx] = 0;
}

// ---------------- pass 1: bin edges into per-bucket regions ----------------
// pairs[slot] = (dstLocal << 23) | src ; bcur[b] = fill count.
__global__ __launch_bounds__(512) void bin_k(const int* __restrict__ src,
                                             const int* __restrict__ dst,
                                             int* __restrict__ bcur,
                                             unsigned int* __restrict__ pairs, int E) {
    __shared__ int h[MAXB];
    __shared__ int cur[MAXB];
    if (threadIdx.x < MAXB) h[threadIdx.x] = 0;
    __syncthreads();
    const int base = blockIdx.x * CHUNK;
    int s_[16], d_[16];
    int n = 0;
#pragma unroll
    for (int u = 0; u < 16; ++u) {
        int e = base + u * 512 + threadIdx.x;
        if (e < E) {
            s_[u] = src[e];
            d_[u] = dst[e];
            atomicAdd(&h[d_[u] >> BSHIFT], 1);
            n = u + 1;                      // validity is monotone in u for fixed tid
        }
    }
    __syncthreads();
    if (threadIdx.x < MAXB) {
        int i = threadIdx.x;
        cur[i] = h[i] ? (i * CAP + atomicAdd(&bcur[i], h[i])) : 0;
    }
    __syncthreads();
#pragma unroll
    for (int u = 0; u < 16; ++u) {
        if (u < n) {
            int b = d_[u] >> BSHIFT;
            int pos = atomicAdd(&cur[b], 1);
            if (pos - b * CAP < CAP)        // overflow guard (never taken for this dist)
                pairs[pos] = ((unsigned int)(d_[u] & ((1 << BSHIFT) - 1)) << 23) |
                             (unsigned int)s_[u];
        }
    }
}

// ---------------- pass 2: per-bucket degree + dis + offsets + sorted scatter -----
// One 512-thread workgroup per bucket; hist/scan/cursors all stay in LDS.
__global__ __launch_bounds__(512) void csr_k(const unsigned int* __restrict__ pairs,
                                             const int* __restrict__ bcur,
                                             int* __restrict__ offs,
                                             int* __restrict__ deg,
                                             float* __restrict__ dis,
                                             int* __restrict__ edge_src, int N) {
    __shared__ int hist[512];
    __shared__ int scan[512];
    __shared__ int cur[512];
    const int b = blockIdx.x;
    const int t = threadIdx.x;
    const int vb = b << BSHIFT;
    const int ebeg = b * CAP;
    int cnt = bcur[b]; cnt = cnt < CAP ? cnt : CAP;
    const int eend = ebeg + cnt;

    hist[t] = 0;
    __syncthreads();
    for (int e = ebeg + t; e < eend; e += 512)
        atomicAdd(&hist[pairs[e] >> 23], 1);
    __syncthreads();

    // inclusive Hillis-Steele scan of 512 with 512 threads
    scan[t] = hist[t];
    __syncthreads();
    for (int o = 1; o < 512; o <<= 1) {
        int a = (t >= o) ? scan[t - o] : 0;
        __syncthreads();
        scan[t] += a;
        __syncthreads();
    }

    {
        int v = vb + t;
        if (v < N) {
            int c = hist[t];
            int base = ebeg + scan[t] - c;      // exclusive, bucket-region-relative
            offs[v] = base;
            deg[v] = c;
            cur[t] = base;
            dis[v] = rsqrtf((float)(c + 1));    // +1 self-loop
        }
    }
    __syncthreads();

    for (int e = ebeg + t; e < eend; e += 512) {
        unsigned int p = pairs[e];
        int pos = atomicAdd(&cur[p >> 23], 1);
        edge_src[pos] = (int)(p & 0x7FFFFFu);
    }
}

// ---------------- MFMA GEMM, LDS-free input staging ----------------
// h1s[r][c] = fp16( dis[r] * sum_k x[r][k] * W1[k][c] ).
// A-fragments: direct float4 global loads of x + cvt (each row read exactly once).
// B-fragments: direct 16B f16x8 loads from w1t (32 KB, L1-resident, all waves reuse).
// LDS = epilogue transpose buffer only (34.8 KB) -> 4 blocks/CU (was 2 at 69.6 KB).

__global__ __launch_bounds__(256) void gemm_k(const float* __restrict__ x,
                                              const _Float16* __restrict__ w1t,
                                              const float* __restrict__ dis,
                                              __half2* __restrict__ h1s2, int N) {
    __shared__ _Float16 es[128][128 + GP];

    const int tid = threadIdx.x;
    const int row0 = blockIdx.x * 128;
    const int wave = tid >> 6, lane = tid & 63;
    const int qr = lane & 15;       // A-row / B-col / D-col index
    const int quad = lane >> 4;     // k-subgroup, D-row group
    const int m0 = wave * 32;       // 32 rows per wave (2 M-tiles)

    int r0 = row0 + m0 + qr;      r0 = r0 < N ? r0 : N - 1;
    int r1 = row0 + m0 + 16 + qr; r1 = r1 < N ? r1 : N - 1;
    const float* xr0 = x + (size_t)r0 * D;
    const float* xr1 = x + (size_t)r1 * D;

    f32x4 acc[2][8] = {};
#pragma unroll
    for (int kt = 0; kt < 4; ++kt) {
        const int kk = kt * 32 + quad * 8;
        float4 fa = *(const float4*)&xr0[kk];
        float4 fb = *(const float4*)&xr0[kk + 4];
        float4 fc = *(const float4*)&xr1[kk];
        float4 fd = *(const float4*)&xr1[kk + 4];
        f16x8 a0, a1;
        a0[0] = (_Float16)fa.x; a0[1] = (_Float16)fa.y;
        a0[2] = (_Float16)fa.z; a0[3] = (_Float16)fa.w;
        a0[4] = (_Float16)fb.x; a0[5] = (_Float16)fb.y;
        a0[6] = (_Float16)fb.z; a0[7] = (_Float16)fb.w;
        a1[0] = (_Float16)fc.x; a1[1] = (_Float16)fc.y;
        a1[2] = (_Float16)fc.z; a1[3] = (_Float16)fc.w;
        a1[4] = (_Float16)fd.x; a1[5] = (_Float16)fd.y;
        a1[6] = (_Float16)fd.z; a1[7] = (_Float16)fd.w;
#pragma unroll
        for (int n = 0; n < 8; ++n) {
            f16x8 b = *(const f16x8*)&w1t[(n * 16 + qr) * 128 + kk];
            acc[0][n] = __builtin_amdgcn_mfma_f32_16x16x32_f16(a0, b, acc[0][n], 0, 0, 0);
            acc[1][n] = __builtin_amdgcn_mfma_f32_16x16x32_f16(a1, b, acc[1][n], 0, 0, 0);
        }
    }

    // dis per (mtile, reg): D row = m0 + mt*16 + quad*4 + r
    float dv[2][4];
#pragma unroll
    for (int mt = 0; mt < 2; ++mt)
#pragma unroll
        for (int r = 0; r < 4; ++r) {
            int rg = row0 + m0 + mt * 16 + quad * 4 + r;
            dv[mt][r] = dis[rg < N ? rg : 0];
        }

    // epilogue: transpose via LDS, coalesced fp16 store
#pragma unroll
    for (int mt = 0; mt < 2; ++mt)
#pragma unroll
        for (int n = 0; n < 8; ++n)
#pragma unroll
            for (int r = 0; r < 4; ++r)
                es[m0 + mt * 16 + quad * 4 + r][n * 16 + qr] =
                    (_Float16)(acc[mt][n][r] * dv[mt][r]);
    __syncthreads();

    // coalesced copy out: 128 rows x 16 int4, 8 per thread
#pragma unroll
    for (int u = 0; u < 8; ++u) {
        int f = u * 256 + tid;
        int r = f >> 4, c8 = f & 15;
        int rg = row0 + r;
        if (rg < N)
            *(int4*)((_Float16*)h1s2 + (size_t)rg * D + c8 * 8) = *(int4*)&es[r][c8 * 8];
    }
}

// ---------------- fused: aggregate layer1 + b1 + relu + W2 matvec ----------------
// one WAVE per node (4 nodes / 256-block); lane l holds features 2l, 2l+1 (half2).
// (R7-proven: 62 µs, fabric-bound)

__global__ __launch_bounds__(256) void agg1_k(const __half2* __restrict__ h1s2,
                                              const int* __restrict__ edge_src,
                                              const int* __restrict__ offs,
                                              const int* __restrict__ deg,
                                              const float* __restrict__ dis,
                                              const float* __restrict__ b1,
                                              const float* __restrict__ W2,
                                              float* __restrict__ g, int N) {
    const int lane = threadIdx.x & 63;
    int v = blockIdx.x * 4 + (threadIdx.x >> 6);
    if (v >= N) return;
    v = __builtin_amdgcn_readfirstlane(v);           // force SGPR: scalar loads below

    __half2 hs = h1s2[v * 64 + lane];                // self-loop (h1s carries dis[src])
    float ax = __low2float(hs), ay = __high2float(hs);

    int beg = __builtin_amdgcn_readfirstlane(offs[v]);
    int end = beg + __builtin_amdgcn_readfirstlane(deg[v]);

    int i = beg;
    for (; i + 8 <= end; i += 8) {                   // 8 gathers in flight
        __half2 h0 = h1s2[edge_src[i + 0] * 64 + lane];
        __half2 h1 = h1s2[edge_src[i + 1] * 64 + lane];
        __half2 h2 = h1s2[edge_src[i + 2] * 64 + lane];
        __half2 h3 = h1s2[edge_src[i + 3] * 64 + lane];
        __half2 h4 = h1s2[edge_src[i + 4] * 64 + lane];
        __half2 h5 = h1s2[edge_src[i + 5] * 64 + lane];
        __half2 h6 = h1s2[edge_src[i + 6] * 64 + lane];
        __half2 h7 = h1s2[edge_src[i + 7] * 64 + lane];
        ax += __low2float(h0) + __low2float(h1) + __low2float(h2) + __low2float(h3)
            + __low2float(h4) + __low2float(h5) + __low2float(h6) + __low2float(h7);
        ay += __high2float(h0) + __high2float(h1) + __high2float(h2) + __high2float(h3)
            + __high2float(h4) + __high2float(h5) + __high2float(h6) + __high2float(h7);
    }
    for (; i < end; ++i) {
        __half2 h0 = h1s2[edge_src[i] * 64 + lane];
        ax += __low2float(h0);
        ay += __high2float(h0);
    }

    const float dv = dis[v];
    const float2 bb = ((const float2*)b1)[lane];
    const float2 w2 = ((const float2*)W2)[lane];
    float vx = fmaxf(fmaf(dv, ax, bb.x), 0.f);
    float vy = fmaxf(fmaf(dv, ay, bb.y), 0.f);
    float p = vx * w2.x + vy * w2.y;
#pragma unroll
    for (int o = 32; o >= 1; o >>= 1) p += __shfl_xor(p, o, 64);
    if (lane == 0) g[v] = dv * p;
}

// ---------------- layer-2 scalar aggregation ----------------

__global__ void agg2_k(const float* __restrict__ g, const int* __restrict__ edge_src,
                       const int* __restrict__ offs, const int* __restrict__ deg,
                       const float* __restrict__ dis, const float* __restrict__ b2,
                       float* __restrict__ out, int N) {
    int v = blockIdx.x * 256 + threadIdx.x;
    if (v >= N) return;
    float acc = g[v];                      // self-loop (g already has dis[src])
    const int beg = offs[v];
    const int end = beg + deg[v];
    for (int i = beg; i < end; ++i) acc += g[edge_src[i]];
    out[v] = fmaf(dis[v], acc, b2[0]);
}

// ---------------- launch ----------------

extern "C" void kernel_launch(void* const* d_in, const int* in_sizes, int n_in,
                              void* d_out, int out_size, void* d_ws, size_t ws_size,
                              hipStream_t stream) {
    const float* x  = (const float*)d_in[0];
    const int*   ei = (const int*)d_in[1];
    const float* W1 = (const float*)d_in[2];
    const float* b1 = (const float*)d_in[3];
    const float* W2 = (const float*)d_in[4];
    const float* b2 = (const float*)d_in[5];
    float* out = (float*)d_out;

    const int N = in_sizes[0] / D;
    const int E = in_sizes[1] / 2;
    const int* srcp = ei;
    const int* dstp = ei + E;
    const int nbuck = (N + (1 << BSHIFT) - 1) >> BSHIFT;   // 196 for N=100k

    char* p = (char*)d_ws;
    auto alloc = [&](size_t bytes) {
        void* q = (void*)p;
        p += (bytes + 255) & ~(size_t)255;
        return q;
    };
    __half2*      h1s2     = (__half2*)alloc((size_t)N * D * sizeof(__half));
    float*        g        = (float*)alloc((size_t)N * sizeof(float));
    float*        dis      = (float*)alloc((size_t)N * sizeof(float));
    int*          offs     = (int*)alloc((size_t)N * sizeof(int));
    int*          deg      = (int*)alloc((size_t)N * sizeof(int));
    int*          edge_src = (int*)alloc((size_t)nbuck * CAP * sizeof(int));
    unsigned int* pairs    = (unsigned int*)alloc((size_t)nbuck * CAP * sizeof(unsigned int));
    _Float16*     w1t      = (_Float16*)alloc((size_t)D * D * sizeof(_Float16));
    int*          bcur     = (int*)alloc(MAXB * sizeof(int));

    const int nb = (N + 255) / 256;

    setup_k<<<(D * D) / 256, 256, 0, stream>>>(W1, w1t, bcur);
    bin_k<<<(E + CHUNK - 1) / CHUNK, 512, 0, stream>>>(srcp, dstp, bcur, pairs, E);
    csr_k<<<nbuck, 512, 0, stream>>>(pairs, bcur, offs, deg, dis, edge_src, N);
    gemm_k<<<(N + 127) / 128, 256, 0, stream>>>(x, w1t, dis, h1s2, N);
    agg1_k<<<(N + 3) / 4, 256, 0, stream>>>(h1s2, edge_src, offs, deg, dis, b1, W2, g, N);
    agg2_k<<<nb, 256, 0, stream>>>(g, edge_src, offs, deg, dis, b2, out, N);
}

// Round 11
// 226.255 us; speedup vs baseline: 1.2180x; 1.0035x over previous
//
#include <hip/hip_runtime.h>
#include <hip/hip_fp16.h>

#define D 128          // feature dim (D_IN == D_H)
#define BSHIFT 9       // bucket = dst >> 9 (512 nodes per bucket)
#define MAXB 512       // max buckets supported (N up to 262144)
#define CHUNK 8192     // edges per bin_k block (16 per thread, 512 threads)
#define CAP 12288      // fixed slots per bucket (mean 8163, sigma ~90 -> 45 sigma slack)
#define GP 8           // LDS pad (halves) -> row stride 272 B, 2-way-conflict-free

typedef _Float16 f16x8 __attribute__((ext_vector_type(8)));
typedef float f32x4 __attribute__((ext_vector_type(4)));

// ---------------- pass 1: bin edges into per-bucket regions ----------------
// pairs[slot] = (dstLocal << 23) | src ; bcur[b] = fill count (memset to 0).
// Block 0 additionally transposes W1 -> fp16 w1t (hidden under the other blocks).
__global__ __launch_bounds__(512) void bin_k(const int* __restrict__ src,
                                             const int* __restrict__ dst,
                                             int* __restrict__ bcur,
                                             unsigned int* __restrict__ pairs,
                                             const float* __restrict__ W1,
                                             _Float16* __restrict__ w1t, int E) {
    __shared__ int h[MAXB];
    __shared__ int cur[MAXB];
    if (threadIdx.x < MAXB) h[threadIdx.x] = 0;
    __syncthreads();
    const int base = blockIdx.x * CHUNK;
    int s_[16], d_[16];
    int n = 0;
#pragma unroll
    for (int u = 0; u < 16; ++u) {
        int e = base + u * 512 + threadIdx.x;
        if (e < E) {
            s_[u] = src[e];
            d_[u] = dst[e];
            atomicAdd(&h[d_[u] >> BSHIFT], 1);
            n = u + 1;                      // validity is monotone in u for fixed tid
        }
    }
    __syncthreads();
    if (threadIdx.x < MAXB) {
        int i = threadIdx.x;
        cur[i] = h[i] ? (i * CAP + atomicAdd(&bcur[i], h[i])) : 0;
    }
    __syncthreads();
#pragma unroll
    for (int u = 0; u < 16; ++u) {
        if (u < n) {
            int b = d_[u] >> BSHIFT;
            int pos = atomicAdd(&cur[b], 1);
            if (pos - b * CAP < CAP)        // overflow guard (never taken for this dist)
                pairs[pos] = ((unsigned int)(d_[u] & ((1 << BSHIFT) - 1)) << 23) |
                             (unsigned int)s_[u];
        }
    }
    if (blockIdx.x == 0) {                  // W1^T -> fp16 (consumed by gemm_k, later)
        for (int idx = threadIdx.x; idx < D * D; idx += 512) {
            int k = idx >> 7, nn = idx & 127;
            w1t[nn * 128 + k] = (_Float16)W1[idx];
        }
    }
}

// ---------------- pass 2: per-bucket degree + dis + offsets + sorted scatter -----
// One 512-thread workgroup per bucket; hist/scan/cursors all stay in LDS.
// Scan = wave-shuffle prefix (2 barriers) instead of Hillis-Steele (18 barriers).
__global__ __launch_bounds__(512) void csr_k(const unsigned int* __restrict__ pairs,
                                             const int* __restrict__ bcur,
                                             int* __restrict__ offs,
                                             int* __restrict__ deg,
                                             float* __restrict__ dis,
                                             int* __restrict__ edge_src, int N) {
    __shared__ int hist[512];
    __shared__ int cur[512];
    __shared__ int wsum[8];
    __shared__ int woff[8];
    const int b = blockIdx.x;
    const int t = threadIdx.x;
    const int lane = t & 63;
    const int wv = t >> 6;
    const int vb = b << BSHIFT;
    const int ebeg = b * CAP;
    int cnt = bcur[b]; cnt = cnt < CAP ? cnt : CAP;
    const int eend = ebeg + cnt;

    hist[t] = 0;
    __syncthreads();
    for (int e = ebeg + t; e < eend; e += 512)
        atomicAdd(&hist[pairs[e] >> 23], 1);
    __syncthreads();

    // inclusive scan of 512: wave shuffle scan + cross-wave offsets
    int c = hist[t];
    int x = c;
#pragma unroll
    for (int o = 1; o < 64; o <<= 1) {
        int y = __shfl_up(x, o, 64);
        if (lane >= o) x += y;
    }
    if (lane == 63) wsum[wv] = x;
    __syncthreads();
    if (t < 8) {
        int s = 0;
        for (int i = 0; i < t; ++i) s += wsum[i];
        woff[t] = s;
    }
    __syncthreads();
    {
        int inc = x + woff[wv];                 // inclusive prefix over all 512
        int base = ebeg + inc - c;              // exclusive, bucket-region-relative
        cur[t] = base;
        int v = vb + t;
        if (v < N) {
            offs[v] = base;
            deg[v] = c;
            dis[v] = rsqrtf((float)(c + 1));    // +1 self-loop
        }
    }
    __syncthreads();

    for (int e = ebeg + t; e < eend; e += 512) {
        unsigned int p = pairs[e];
        int pos = atomicAdd(&cur[p >> 23], 1);
        edge_src[pos] = (int)(p & 0x7FFFFFu);
    }
}

// ---------------- MFMA GEMM: h1s[r][c] = fp16( dis[r] * sum_k x[r][k] * W1[k][c] )
// 128-row block, full K=N=128 in LDS, v_mfma_f32_16x16x32_f16, fp32 accum.
// (R7-proven version; LDS staging beats direct-global B loads — R10 post-mortem)

__global__ __launch_bounds__(256) void gemm_k(const float* __restrict__ x,
                                              const _Float16* __restrict__ w1t,
                                              const float* __restrict__ dis,
                                              __half2* __restrict__ h1s2, int N) {
    __shared__ _Float16 xs[128][128 + GP];
    __shared__ _Float16 ws[128][128 + GP];   // ws[n][k]

    const int tid = threadIdx.x;
    const int row0 = blockIdx.x * 128;

    // stage x (fp32 -> fp16): 128 rows x 32 float4, 16 per thread
#pragma unroll
    for (int u = 0; u < 16; ++u) {
        int f = u * 256 + tid;
        int r = f >> 5, c4 = f & 31;
        int rg = row0 + r; rg = rg < N ? rg : N - 1;
        float4 v = ((const float4*)(x + (size_t)rg * D))[c4];
        union { _Float16 h[4]; uint2 u2; } tmp;
        tmp.h[0] = (_Float16)v.x; tmp.h[1] = (_Float16)v.y;
        tmp.h[2] = (_Float16)v.z; tmp.h[3] = (_Float16)v.w;
        *(uint2*)&xs[r][c4 * 4] = tmp.u2;
    }
    // stage w1t (already fp16, row-major [n][k]): 128 rows x 16 int4, 8 per thread
#pragma unroll
    for (int u = 0; u < 8; ++u) {
        int f = u * 256 + tid;
        int r = f >> 4, c8 = f & 15;
        int4 v = ((const int4*)(w1t + r * 128))[c8];
        *(int4*)&ws[r][c8 * 8] = v;
    }
    __syncthreads();

    const int wave = tid >> 6, lane = tid & 63;
    const int qr = lane & 15;       // A-row / B-col / D-col index
    const int quad = lane >> 4;     // k-subgroup, D-row group
    const int m0 = wave * 32;       // 32 rows per wave (2 M-tiles)

    f32x4 acc[2][8] = {};
#pragma unroll
    for (int kt = 0; kt < 4; ++kt) {
        const int kk = kt * 32 + quad * 8;
        f16x8 a0 = *(const f16x8*)&xs[m0 + qr][kk];
        f16x8 a1 = *(const f16x8*)&xs[m0 + 16 + qr][kk];
#pragma unroll
        for (int n = 0; n < 8; ++n) {
            f16x8 b = *(const f16x8*)&ws[n * 16 + qr][kk];
            acc[0][n] = __builtin_amdgcn_mfma_f32_16x16x32_f16(a0, b, acc[0][n], 0, 0, 0);
            acc[1][n] = __builtin_amdgcn_mfma_f32_16x16x32_f16(a1, b, acc[1][n], 0, 0, 0);
        }
    }

    // dis per (mtile, reg): D row = m0 + mt*16 + quad*4 + r
    float dv[2][4];
#pragma unroll
    for (int mt = 0; mt < 2; ++mt)
#pragma unroll
        for (int r = 0; r < 4; ++r) {
            int rg = row0 + m0 + mt * 16 + quad * 4 + r;
            dv[mt][r] = dis[rg < N ? rg : 0];
        }

    __syncthreads();   // all waves done reading xs before reuse
#pragma unroll
    for (int mt = 0; mt < 2; ++mt)
#pragma unroll
        for (int n = 0; n < 8; ++n)
#pragma unroll
            for (int r = 0; r < 4; ++r)
                xs[m0 + mt * 16 + quad * 4 + r][n * 16 + qr] =
                    (_Float16)(acc[mt][n][r] * dv[mt][r]);
    __syncthreads();

    // coalesced copy out: 128 rows x 16 int4, 8 per thread
#pragma unroll
    for (int u = 0; u < 8; ++u) {
        int f = u * 256 + tid;
        int r = f >> 4, c8 = f & 15;
        int rg = row0 + r;
        if (rg < N)
            *(int4*)((_Float16*)h1s2 + (size_t)rg * D + c8 * 8) = *(int4*)&xs[r][c8 * 8];
    }
}

// ---------------- fused: aggregate layer1 + b1 + relu + W2 matvec ----------------
// one WAVE per node (4 nodes / 256-block); lane l holds features 2l, 2l+1 (half2).
// (R7-proven: 62 µs, fabric-bound floor)

__global__ __launch_bounds__(256) void agg1_k(const __half2* __restrict__ h1s2,
                                              const int* __restrict__ edge_src,
                                              const int* __restrict__ offs,
                                              const int* __restrict__ deg,
                                              const float* __restrict__ dis,
                                              const float* __restrict__ b1,
                                              const float* __restrict__ W2,
                                              float* __restrict__ g, int N) {
    const int lane = threadIdx.x & 63;
    int v = blockIdx.x * 4 + (threadIdx.x >> 6);
    if (v >= N) return;
    v = __builtin_amdgcn_readfirstlane(v);           // force SGPR: scalar loads below

    __half2 hs = h1s2[v * 64 + lane];                // self-loop (h1s carries dis[src])
    float ax = __low2float(hs), ay = __high2float(hs);

    int beg = __builtin_amdgcn_readfirstlane(offs[v]);
    int end = beg + __builtin_amdgcn_readfirstlane(deg[v]);

    int i = beg;
    for (; i + 8 <= end; i += 8) {                   // 8 gathers in flight
        __half2 h0 = h1s2[edge_src[i + 0] * 64 + lane];
        __half2 h1 = h1s2[edge_src[i + 1] * 64 + lane];
        __half2 h2 = h1s2[edge_src[i + 2] * 64 + lane];
        __half2 h3 = h1s2[edge_src[i + 3] * 64 + lane];
        __half2 h4 = h1s2[edge_src[i + 4] * 64 + lane];
        __half2 h5 = h1s2[edge_src[i + 5] * 64 + lane];
        __half2 h6 = h1s2[edge_src[i + 6] * 64 + lane];
        __half2 h7 = h1s2[edge_src[i + 7] * 64 + lane];
        ax += __low2float(h0) + __low2float(h1) + __low2float(h2) + __low2float(h3)
            + __low2float(h4) + __low2float(h5) + __low2float(h6) + __low2float(h7);
        ay += __high2float(h0) + __high2float(h1) + __high2float(h2) + __high2float(h3)
            + __high2float(h4) + __high2float(h5) + __high2float(h6) + __high2float(h7);
    }
    for (; i < end; ++i) {
        __half2 h0 = h1s2[edge_src[i] * 64 + lane];
        ax += __low2float(h0);
        ay += __high2float(h0);
    }

    const float dv = dis[v];
    const float2 bb = ((const float2*)b1)[lane];
    const float2 w2 = ((const float2*)W2)[lane];
    float vx = fmaxf(fmaf(dv, ax, bb.x), 0.f);
    float vy = fmaxf(fmaf(dv, ay, bb.y), 0.f);
    float p = vx * w2.x + vy * w2.y;
#pragma unroll
    for (int o = 32; o >= 1; o >>= 1) p += __shfl_xor(p, o, 64);
    if (lane == 0) g[v] = dv * p;
}

// ---------------- layer-2 scalar aggregation ----------------

__global__ void agg2_k(const float* __restrict__ g, const int* __restrict__ edge_src,
                       const int* __restrict__ offs, const int* __restrict__ deg,
                       const float* __restrict__ dis, const float* __restrict__ b2,
                       float* __restrict__ out, int N) {
    int v = blockIdx.x * 256 + threadIdx.x;
    if (v >= N) return;
    float acc = g[v];                      // self-loop (g already has dis[src])
    const int beg = offs[v];
    const int end = beg + deg[v];
    for (int i = beg; i < end; ++i) acc += g[edge_src[i]];
    out[v] = fmaf(dis[v], acc, b2[0]);
}

// ---------------- launch ----------------

extern "C" void kernel_launch(void* const* d_in, const int* in_sizes, int n_in,
                              void* d_out, int out_size, void* d_ws, size_t ws_size,
                              hipStream_t stream) {
    const float* x  = (const float*)d_in[0];
    const int*   ei = (const int*)d_in[1];
    const float* W1 = (const float*)d_in[2];
    const float* b1 = (const float*)d_in[3];
    const float* W2 = (const float*)d_in[4];
    const float* b2 = (const float*)d_in[5];
    float* out = (float*)d_out;

    const int N = in_sizes[0] / D;
    const int E = in_sizes[1] / 2;
    const int* srcp = ei;
    const int* dstp = ei + E;
    const int nbuck = (N + (1 << BSHIFT) - 1) >> BSHIFT;   // 196 for N=100k

    char* p = (char*)d_ws;
    auto alloc = [&](size_t bytes) {
        void* q = (void*)p;
        p += (bytes + 255) & ~(size_t)255;
        return q;
    };
    __half2*      h1s2     = (__half2*)alloc((size_t)N * D * sizeof(__half));
    float*        g        = (float*)alloc((size_t)N * sizeof(float));
    float*        dis      = (float*)alloc((size_t)N * sizeof(float));
    int*          offs     = (int*)alloc((size_t)N * sizeof(int));
    int*          deg      = (int*)alloc((size_t)N * sizeof(int));
    int*          edge_src = (int*)alloc((size_t)nbuck * CAP * sizeof(int));
    unsigned int* pairs    = (unsigned int*)alloc((size_t)nbuck * CAP * sizeof(unsigned int));
    _Float16*     w1t      = (_Float16*)alloc((size_t)D * D * sizeof(_Float16));
    int*          bcur     = (int*)alloc(MAXB * sizeof(int));

    const int nb = (N + 255) / 256;

    hipMemsetAsync(bcur, 0, MAXB * sizeof(int), stream);
    bin_k<<<(E + CHUNK - 1) / CHUNK, 512, 0, stream>>>(srcp, dstp, bcur, pairs, W1, w1t, E);
    csr_k<<<nbuck, 512, 0, stream>>>(pairs, bcur, offs, deg, dis, edge_src, N);
    gemm_k<<<(N + 127) / 128, 256, 0, stream>>>(x, w1t, dis, h1s2, N);
    agg1_k<<<(N + 3) / 4, 256, 0, stream>>>(h1s2, edge_src, offs, deg, dis, b1, W2, g, N);
    agg2_k<<<nb, 256, 0, stream>>>(g, edge_src, offs, deg, dis, b2, out, N);
}

// Round 12
// 214.319 us; speedup vs baseline: 1.2858x; 1.0557x over previous
//
#include <hip/hip_runtime.h>
#include <hip/hip_fp16.h>

#define D 128          // feature dim (D_IN == D_H)
#define BSHIFT 9       // bucket = dst >> 9 (512 nodes per bucket)
#define MAXB 512       // max buckets supported (N up to 262144)
#define CHUNK 8192     // edges per bin_k block (16 per thread, 512 threads)
#define CAP 12288      // fixed slots per bucket (mean 8163, sigma ~90 -> 45 sigma slack)
#define GP 8           // LDS pad (halves) -> row stride 272 B, 2-way-conflict-free

typedef _Float16 f16x8 __attribute__((ext_vector_type(8)));
typedef float f32x4 __attribute__((ext_vector_type(4)));

// ---------------- setup: W1 transpose to fp16 + zero bucket cursors ----------------
// (separate kernel: folding this into bin_k block 0 cost +12 us — R11 post-mortem)
__global__ void setup_k(const float* __restrict__ W1, _Float16* __restrict__ w1t,
                        int* __restrict__ bcur) {
    int idx = blockIdx.x * 256 + threadIdx.x;   // 16384 total
    int k = idx >> 7, n = idx & 127;
    w1t[n * 128 + k] = (_Float16)W1[idx];
    if (idx < MAXB) bcur[idx] = 0;
}

// ---------------- pass 1: bin edges into per-bucket regions ----------------
// pairs[slot] = (dstLocal << 23) | src ; bcur[b] = fill count.
__global__ __launch_bounds__(512) void bin_k(const int* __restrict__ src,
                                             const int* __restrict__ dst,
                                             int* __restrict__ bcur,
                                             unsigned int* __restrict__ pairs, int E) {
    __shared__ int h[MAXB];
    __shared__ int cur[MAXB];
    if (threadIdx.x < MAXB) h[threadIdx.x] = 0;
    __syncthreads();
    const int base = blockIdx.x * CHUNK;
    int s_[16], d_[16];
    int n = 0;
#pragma unroll
    for (int u = 0; u < 16; ++u) {
        int e = base + u * 512 + threadIdx.x;
        if (e < E) {
            s_[u] = src[e];
            d_[u] = dst[e];
            atomicAdd(&h[d_[u] >> BSHIFT], 1);
            n = u + 1;                      // validity is monotone in u for fixed tid
        }
    }
    __syncthreads();
    if (threadIdx.x < MAXB) {
        int i = threadIdx.x;
        cur[i] = h[i] ? (i * CAP + atomicAdd(&bcur[i], h[i])) : 0;
    }
    __syncthreads();
#pragma unroll
    for (int u = 0; u < 16; ++u) {
        if (u < n) {
            int b = d_[u] >> BSHIFT;
            int pos = atomicAdd(&cur[b], 1);
            if (pos - b * CAP < CAP)        // overflow guard (never taken for this dist)
                pairs[pos] = ((unsigned int)(d_[u] & ((1 << BSHIFT) - 1)) << 23) |
                             (unsigned int)s_[u];
        }
    }
}

// ---------------- pass 2: per-bucket degree + dis + offsets + sorted scatter -----
// One 512-thread workgroup per bucket; hist/scan/cursors all stay in LDS.
// Scan = wave-shuffle prefix (2 barriers; replaces 18-barrier Hillis-Steele).
__global__ __launch_bounds__(512) void csr_k(const unsigned int* __restrict__ pairs,
                                             const int* __restrict__ bcur,
                                             int* __restrict__ offs,
                                             int* __restrict__ deg,
                                             float* __restrict__ dis,
                                             int* __restrict__ edge_src, int N) {
    __shared__ int hist[512];
    __shared__ int cur[512];
    __shared__ int wsum[8];
    __shared__ int woff[8];
    const int b = blockIdx.x;
    const int t = threadIdx.x;
    const int lane = t & 63;
    const int wv = t >> 6;
    const int vb = b << BSHIFT;
    const int ebeg = b * CAP;
    int cnt = bcur[b]; cnt = cnt < CAP ? cnt : CAP;
    const int eend = ebeg + cnt;

    hist[t] = 0;
    __syncthreads();
    for (int e = ebeg + t; e < eend; e += 512)
        atomicAdd(&hist[pairs[e] >> 23], 1);
    __syncthreads();

    // inclusive scan of 512: wave shuffle scan + cross-wave offsets
    int c = hist[t];
    int x = c;
#pragma unroll
    for (int o = 1; o < 64; o <<= 1) {
        int y = __shfl_up(x, o, 64);
        if (lane >= o) x += y;
    }
    if (lane == 63) wsum[wv] = x;
    __syncthreads();
    if (t < 8) {
        int s = 0;
        for (int i = 0; i < t; ++i) s += wsum[i];
        woff[t] = s;
    }
    __syncthreads();
    {
        int inc = x + woff[wv];                 // inclusive prefix over all 512
        int base = ebeg + inc - c;              // exclusive, bucket-region-relative
        cur[t] = base;
        int v = vb + t;
        if (v < N) {
            offs[v] = base;
            deg[v] = c;
            dis[v] = rsqrtf((float)(c + 1));    // +1 self-loop
        }
    }
    __syncthreads();

    for (int e = ebeg + t; e < eend; e += 512) {
        unsigned int p = pairs[e];
        int pos = atomicAdd(&cur[p >> 23], 1);
        edge_src[pos] = (int)(p & 0x7FFFFFu);
    }
}

// ---------------- MFMA GEMM: h1s[r][c] = fp16( dis[r] * sum_k x[r][k] * W1[k][c] )
// 128-row block, full K=N=128 in LDS, v_mfma_f32_16x16x32_f16, fp32 accum.
// (R7-proven; LDS staging beats direct-global operand loads — R10 post-mortem)

__global__ __launch_bounds__(256) void gemm_k(const float* __restrict__ x,
                                              const _Float16* __restrict__ w1t,
                                              const float* __restrict__ dis,
                                              __half2* __restrict__ h1s2, int N) {
    __shared__ _Float16 xs[128][128 + GP];
    __shared__ _Float16 ws[128][128 + GP];   // ws[n][k]

    const int tid = threadIdx.x;
    const int row0 = blockIdx.x * 128;

    // stage x (fp32 -> fp16): 128 rows x 32 float4, 16 per thread
#pragma unroll
    for (int u = 0; u < 16; ++u) {
        int f = u * 256 + tid;
        int r = f >> 5, c4 = f & 31;
        int rg = row0 + r; rg = rg < N ? rg : N - 1;
        float4 v = ((const float4*)(x + (size_t)rg * D))[c4];
        union { _Float16 h[4]; uint2 u2; } tmp;
        tmp.h[0] = (_Float16)v.x; tmp.h[1] = (_Float16)v.y;
        tmp.h[2] = (_Float16)v.z; tmp.h[3] = (_Float16)v.w;
        *(uint2*)&xs[r][c4 * 4] = tmp.u2;
    }
    // stage w1t (already fp16, row-major [n][k]): 128 rows x 16 int4, 8 per thread
#pragma unroll
    for (int u = 0; u < 8; ++u) {
        int f = u * 256 + tid;
        int r = f >> 4, c8 = f & 15;
        int4 v = ((const int4*)(w1t + r * 128))[c8];
        *(int4*)&ws[r][c8 * 8] = v;
    }
    __syncthreads();

    const int wave = tid >> 6, lane = tid & 63;
    const int qr = lane & 15;       // A-row / B-col / D-col index
    const int quad = lane >> 4;     // k-subgroup, D-row group
    const int m0 = wave * 32;       // 32 rows per wave (2 M-tiles)

    f32x4 acc[2][8] = {};
#pragma unroll
    for (int kt = 0; kt < 4; ++kt) {
        const int kk = kt * 32 + quad * 8;
        f16x8 a0 = *(const f16x8*)&xs[m0 + qr][kk];
        f16x8 a1 = *(const f16x8*)&xs[m0 + 16 + qr][kk];
#pragma unroll
        for (int n = 0; n < 8; ++n) {
            f16x8 b = *(const f16x8*)&ws[n * 16 + qr][kk];
            acc[0][n] = __builtin_amdgcn_mfma_f32_16x16x32_f16(a0, b, acc[0][n], 0, 0, 0);
            acc[1][n] = __builtin_amdgcn_mfma_f32_16x16x32_f16(a1, b, acc[1][n], 0, 0, 0);
        }
    }

    // dis per (mtile, reg): D row = m0 + mt*16 + quad*4 + r
    float dv[2][4];
#pragma unroll
    for (int mt = 0; mt < 2; ++mt)
#pragma unroll
        for (int r = 0; r < 4; ++r) {
            int rg = row0 + m0 + mt * 16 + quad * 4 + r;
            dv[mt][r] = dis[rg < N ? rg : 0];
        }

    __syncthreads();   // all waves done reading xs before reuse
#pragma unroll
    for (int mt = 0; mt < 2; ++mt)
#pragma unroll
        for (int n = 0; n < 8; ++n)
#pragma unroll
            for (int r = 0; r < 4; ++r)
                xs[m0 + mt * 16 + quad * 4 + r][n * 16 + qr] =
                    (_Float16)(acc[mt][n][r] * dv[mt][r]);
    __syncthreads();

    // coalesced copy out: 128 rows x 16 int4, 8 per thread
#pragma unroll
    for (int u = 0; u < 8; ++u) {
        int f = u * 256 + tid;
        int r = f >> 4, c8 = f & 15;
        int rg = row0 + r;
        if (rg < N)
            *(int4*)((_Float16*)h1s2 + (size_t)rg * D + c8 * 8) = *(int4*)&xs[r][c8 * 8];
    }
}

// ---------------- fused: aggregate layer1 + b1 + relu + W2 matvec ----------------
// one WAVE per node (4 nodes / 256-block); lane l holds features 2l, 2l+1 (half2).
// (R7-proven: 62 µs, fabric-bound floor — do not restructure; R6/R8 both lost >2x)

__global__ __launch_bounds__(256) void agg1_k(const __half2* __restrict__ h1s2,
                                              const int* __restrict__ edge_src,
                                              const int* __restrict__ offs,
                                              const int* __restrict__ deg,
                                              const float* __restrict__ dis,
                                              const float* __restrict__ b1,
                                              const float* __restrict__ W2,
                                              float* __restrict__ g, int N) {
    const int lane = threadIdx.x & 63;
    int v = blockIdx.x * 4 + (threadIdx.x >> 6);
    if (v >= N) return;
    v = __builtin_amdgcn_readfirstlane(v);           // force SGPR: scalar loads below

    __half2 hs = h1s2[v * 64 + lane];                // self-loop (h1s carries dis[src])
    float ax = __low2float(hs), ay = __high2float(hs);

    int beg = __builtin_amdgcn_readfirstlane(offs[v]);
    int end = beg + __builtin_amdgcn_readfirstlane(deg[v]);

    int i = beg;
    for (; i + 8 <= end; i += 8) {                   // 8 gathers in flight
        __half2 h0 = h1s2[edge_src[i + 0] * 64 + lane];
        __half2 h1 = h1s2[edge_src[i + 1] * 64 + lane];
        __half2 h2 = h1s2[edge_src[i + 2] * 64 + lane];
        __half2 h3 = h1s2[edge_src[i + 3] * 64 + lane];
        __half2 h4 = h1s2[edge_src[i + 4] * 64 + lane];
        __half2 h5 = h1s2[edge_src[i + 5] * 64 + lane];
        __half2 h6 = h1s2[edge_src[i + 6] * 64 + lane];
        __half2 h7 = h1s2[edge_src[i + 7] * 64 + lane];
        ax += __low2float(h0) + __low2float(h1) + __low2float(h2) + __low2float(h3)
            + __low2float(h4) + __low2float(h5) + __low2float(h6) + __low2float(h7);
        ay += __high2float(h0) + __high2float(h1) + __high2float(h2) + __high2float(h3)
            + __high2float(h4) + __high2float(h5) + __high2float(h6) + __high2float(h7);
    }
    for (; i < end; ++i) {
        __half2 h0 = h1s2[edge_src[i] * 64 + lane];
        ax += __low2float(h0);
        ay += __high2float(h0);
    }

    const float dv = dis[v];
    const float2 bb = ((const float2*)b1)[lane];
    const float2 w2 = ((const float2*)W2)[lane];
    float vx = fmaxf(fmaf(dv, ax, bb.x), 0.f);
    float vy = fmaxf(fmaf(dv, ay, bb.y), 0.f);
    float p = vx * w2.x + vy * w2.y;
#pragma unroll
    for (int o = 32; o >= 1; o >>= 1) p += __shfl_xor(p, o, 64);
    if (lane == 0) g[v] = dv * p;
}

// ---------------- layer-2 scalar aggregation ----------------

__global__ void agg2_k(const float* __restrict__ g, const int* __restrict__ edge_src,
                       const int* __restrict__ offs, const int* __restrict__ deg,
                       const float* __restrict__ dis, const float* __restrict__ b2,
                       float* __restrict__ out, int N) {
    int v = blockIdx.x * 256 + threadIdx.x;
    if (v >= N) return;
    float acc = g[v];                      // self-loop (g already has dis[src])
    const int beg = offs[v];
    const int end = beg + deg[v];
    for (int i = beg; i < end; ++i) acc += g[edge_src[i]];
    out[v] = fmaf(dis[v], acc, b2[0]);
}

// ---------------- launch ----------------

extern "C" void kernel_launch(void* const* d_in, const int* in_sizes, int n_in,
                              void* d_out, int out_size, void* d_ws, size_t ws_size,
                              hipStream_t stream) {
    const float* x  = (const float*)d_in[0];
    const int*   ei = (const int*)d_in[1];
    const float* W1 = (const float*)d_in[2];
    const float* b1 = (const float*)d_in[3];
    const float* W2 = (const float*)d_in[4];
    const float* b2 = (const float*)d_in[5];
    float* out = (float*)d_out;

    const int N = in_sizes[0] / D;
    const int E = in_sizes[1] / 2;
    const int* srcp = ei;
    const int* dstp = ei + E;
    const int nbuck = (N + (1 << BSHIFT) - 1) >> BSHIFT;   // 196 for N=100k

    char* p = (char*)d_ws;
    auto alloc = [&](size_t bytes) {
        void* q = (void*)p;
        p += (bytes + 255) & ~(size_t)255;
        return q;
    };
    __half2*      h1s2     = (__half2*)alloc((size_t)N * D * sizeof(__half));
    float*        g        = (float*)alloc((size_t)N * sizeof(float));
    float*        dis      = (float*)alloc((size_t)N * sizeof(float));
    int*          offs     = (int*)alloc((size_t)N * sizeof(int));
    int*          deg      = (int*)alloc((size_t)N * sizeof(int));
    int*          edge_src = (int*)alloc((size_t)nbuck * CAP * sizeof(int));
    unsigned int* pairs    = (unsigned int*)alloc((size_t)nbuck * CAP * sizeof(unsigned int));
    _Float16*     w1t      = (_Float16*)alloc((size_t)D * D * sizeof(_Float16));
    int*          bcur     = (int*)alloc(MAXB * sizeof(int));

    const int nb = (N + 255) / 256;

    setup_k<<<(D * D) / 256, 256, 0, stream>>>(W1, w1t, bcur);
    bin_k<<<(E + CHUNK - 1) / CHUNK, 512, 0, stream>>>(srcp, dstp, bcur, pairs, E);
    csr_k<<<nbuck, 512, 0, stream>>>(pairs, bcur, offs, deg, dis, edge_src, N);
    gemm_k<<<(N + 127) / 128, 256, 0, stream>>>(x, w1t, dis, h1s2, N);
    agg1_k<<<(N + 3) / 4, 256, 0, stream>>>(h1s2, edge_src, offs, deg, dis, b1, W2, g, N);
    agg2_k<<<nb, 256, 0, stream>>>(g, edge_src, offs, deg, dis, b2, out, N);
}